// Round 2
// baseline (251.594 us; speedup 1.0000x reference)
//
#include <hip/hip_runtime.h>
#include <hip/hip_bf16.h>

// SequentialEdge: B=256, R=256, A=8, D=2.
// Output: 5 chunks (i=-2..2), chunk i = B*(R-|i|)*64 rows of [node_in, node_out, i+2],
// -1 rows where chain differs; trailing scalar 5. Total ints = 62,619,648 (+1).
//
// R1 design: one thread per 4 consecutive edges (edge-quad). 4 edges aligned to 4
// always share one residue pair -> ONE decode + ONE chain compare per 48B output.
// Stage 12 ints/thread in LDS (swizzled), then 3 coalesced int4 store passes/block.
//
// Chunk table (edge starts): 0 / 4,161,536 / 8,339,456 / 12,533,760 / 16,711,680
// per-graph edges: 16256 / 16320 / 16384 / 16320 / 16256. E_TOTAL = 20,873,216.

#define E_TOTAL   20873216u
#define INT_TOTAL 62619648u

__global__ __launch_bounds__(256)
void seqedge_kernel(const int* __restrict__ chain, int* __restrict__ out) {
    __shared__ int lds[3200];   // 12.5 KB, swizzled
    const unsigned tid = threadIdx.x;
    const unsigned gid = blockIdx.x * 256u + tid;
    const unsigned e0  = gid * 4u;            // first edge of this thread's quad

    // ---- chunk decode (once per 4 edges) ----
    unsigned g, rem; int i, lo, rel;
    if (e0 < 4161536u)       { g = e0 / 16256u;                    rem = e0 - g * 16256u; i = -2; lo = 2; rel = 0; }
    else if (e0 < 8339456u)  { unsigned eo = e0 - 4161536u;  g = eo / 16320u; rem = eo - g * 16320u; i = -1; lo = 1; rel = 1; }
    else if (e0 < 12533760u) { unsigned eo = e0 - 8339456u;  g = eo >> 14;    rem = eo & 16383u;     i = 0;  lo = 0; rel = 2; }
    else if (e0 < 16711680u) { unsigned eo = e0 - 12533760u; g = eo / 16320u; rem = eo - g * 16320u; i = 1;  lo = 0; rel = 3; }
    else                     { unsigned eo = e0 - 16711680u; g = eo / 16256u; rem = eo - g * 16256u; i = 2;  lo = 0; rel = 4; }

    const unsigned rl  = (rem >> 6) + (unsigned)lo;  // local residue
    const unsigned ai  = (rem >> 3) & 7u;            // in-atom (same for all 4 edges)
    const unsigned ao0 = rem & 7u;                   // 0 or 4 (quad is 4-aligned)
    const int res_in  = (int)(g * 256u + rl);
    const int res_out = res_in + i;
    const bool same = chain[res_in] == chain[res_out];

    const int x  = same ? res_in * 8 + (int)ai : -1;
    const int r  = same ? rel : -1;
    const int yb = res_out * 8 + (int)ao0;
    const int y0 = same ? yb     : -1;
    const int y1 = same ? yb + 1 : -1;
    const int y2 = same ? yb + 2 : -1;
    const int y3 = same ? yb + 3 : -1;

    // ---- stage 12 ints to LDS (swizzled: stride 12 dwords + rotation) ----
    // base(c) = 12c + 16*(c>>5) + 4*((c>>3)&3): no overlap, b128-aligned,
    // colliding lane pairs land on distinct 4-bank windows (balanced, conflict-free).
    const unsigned wbase = 12u * tid + 16u * (tid >> 5) + 4u * ((tid >> 3) & 3u);
    int4* ldsv = reinterpret_cast<int4*>(&lds[wbase]);
    ldsv[0] = make_int4(x,  y0, r,  x);
    ldsv[1] = make_int4(y1, r,  x,  y2);
    ldsv[2] = make_int4(r,  x,  y3, r);

    __syncthreads();

    // ---- coalesced write-out: block owns int4 range [blockIdx*768, +768) ----
    const unsigned out_base = blockIdx.x * 768u;
    int4* outv = reinterpret_cast<int4*>(out);
    #pragma unroll
    for (unsigned s = 0; s < 3; ++s) {
        const unsigned m    = s * 256u + tid;      // int4 index within block
        const unsigned c    = m / 3u;              // source chunk (writer tid)
        const unsigned rsub = m - c * 3u;          // which int4 of that chunk
        const unsigned pb   = 12u * c + 16u * (c >> 5) + 4u * ((c >> 3) & 3u) + 4u * rsub;
        outv[out_base + m] = *reinterpret_cast<const int4*>(&lds[pb]);
    }

    if (gid == 0u) out[INT_TOTAL] = 5;   // trailing scalar: num_relation
}

extern "C" void kernel_launch(void* const* d_in, const int* in_sizes, int n_in,
                              void* d_out, int out_size, void* d_ws, size_t ws_size,
                              hipStream_t stream) {
    const int* chain_id = (const int*)d_in[0];
    int* out = (int*)d_out;
    // E_TOTAL/4 = 5,218,304 quads; /256 = 20384 blocks exactly (no tail).
    seqedge_kernel<<<20384, 256, 0, stream>>>(chain_id, out);
}